// Round 4
// baseline (238.026 us; speedup 1.0000x reference)
//
#include <hip/hip_runtime.h>
#include <math.h>

#define LUTN 1024
#define LUTSCALE 512.0f
#define NBINS 50048        // >= N, multiple of 4 (uchar-packed LDS histogram width)
#define HCW (NBINS / 4)    // 12512 packed words = 50 KB LDS
#define CHSH 12            // edge chunk = 4096 edges per histogram block

// ---------------- K1: front — fused role-split: hist blocks [0,P) + prep blocks [P,P+PREPB) --
// hist role: per-chunk LDS histograms, two phases over ONE 50KB array (dst+rank, then src).
// prep role: M table, LUT, feat->bf16, loc->float4. Independent inputs; no cross-role deps.

__global__ __launch_bounds__(256) void front_kernel(
    const float* __restrict__ embed, const float* __restrict__ G_w,
    const float* __restrict__ boundaries, const float* __restrict__ feat,
    const float* __restrict__ loc,
    const int* __restrict__ src, const int* __restrict__ dst,
    float* __restrict__ M, int* __restrict__ lut,
    unsigned short* __restrict__ featH, float4* __restrict__ loc4,
    unsigned char* __restrict__ pcnt, unsigned char* __restrict__ psrc,
    unsigned char* __restrict__ rnk8,
    int N, int E, int P, int PREPB) {

    __shared__ unsigned int h[HCW];   // 50 KB -> 3 blocks/CU for both roles

    if (blockIdx.x < P) {
        // ---- hist role ----
        const int base = blockIdx.x << CHSH;
        const int lim  = min(E - base, 1 << CHSH);

        for (int i = threadIdx.x; i < HCW; i += 256) h[i] = 0u;
        __syncthreads();
        for (int t = threadIdx.x; t < lim; t += 256) {
            const int e = base + t;
            const int dd = dst[e];
            const unsigned sh = (unsigned)(dd & 3) * 8u;
            unsigned old = atomicAdd(&h[dd >> 2], 1u << sh);
            rnk8[e] = (unsigned char)((old >> sh) & 0xFFu);
        }
        __syncthreads();
        unsigned int* gc = (unsigned int*)(pcnt + (size_t)blockIdx.x * NBINS);
        for (int i = threadIdx.x; i < HCW; i += 256) gc[i] = h[i];
        __syncthreads();

        for (int i = threadIdx.x; i < HCW; i += 256) h[i] = 0u;
        __syncthreads();
        for (int t = threadIdx.x; t < lim; t += 256) {
            const int s = src[base + t];
            atomicAdd(&h[s >> 2], 1u << ((unsigned)(s & 3) * 8u));
        }
        __syncthreads();
        unsigned int* gs = (unsigned int*)(psrc + (size_t)blockIdx.x * NBINS);
        for (int i = threadIdx.x; i < HCW; i += 256) gs[i] = h[i];
        return;
    }

    // ---- prep role ----
    const int gid = (blockIdx.x - P) * 256 + threadIdx.x;
    const int gsz = PREPB * 256;
    for (int i = gid; i < 4096; i += gsz) {
        int b = i >> 6, f = i & 63;
        float acc = 0.f;
        #pragma unroll
        for (int dd = 0; dd < 32; ++dd) acc += embed[b * 32 + dd] * G_w[f * 32 + dd];
        M[i] = acc;
    }
    for (int i = gid; i < LUTN; i += gsz) {
        float left = (float)i * (1.0f / LUTSCALE);
        int c = 0;
        for (int j = 0; j < 63; ++j) c += (boundaries[j] < left) ? 1 : 0;
        lut[i] = c;
    }
    const int nq = N * 16;   // N*64/4
    for (int i = gid; i < nq; i += gsz) {
        float4 v = ((const float4*)feat)[i];
        unsigned ux = __float_as_uint(v.x), uy = __float_as_uint(v.y);
        unsigned uz = __float_as_uint(v.z), uw = __float_as_uint(v.w);
        ushort4 hh;
        hh.x = (unsigned short)((ux + 0x7FFFu + ((ux >> 16) & 1u)) >> 16);
        hh.y = (unsigned short)((uy + 0x7FFFu + ((uy >> 16) & 1u)) >> 16);
        hh.z = (unsigned short)((uz + 0x7FFFu + ((uz >> 16) & 1u)) >> 16);
        hh.w = (unsigned short)((uw + 0x7FFFu + ((uw >> 16) & 1u)) >> 16);
        ((ushort4*)featH)[i] = hh;
    }
    for (int i = gid; i < N; i += gsz)
        loc4[i] = make_float4(loc[3 * i], loc[3 * i + 1], loc[3 * i + 2], 0.f);
}

// ---------------- K2: merge+scan fused (1024-thread d-chunks, matches co[d>>10]) -------------
// cnt[d] = in-degree; pcnt[p][d] -> exclusive chunk base; d2w[d] = rsqrt(out_deg);
// then block-scan of cnt inline -> startv (chunk-local exclusive) + part (chunk total).

__global__ __launch_bounds__(1024) void merge_scan_kernel(
    unsigned char* __restrict__ pcnt, const unsigned char* __restrict__ psrc,
    int* __restrict__ cnt, float* __restrict__ d2w,
    int* __restrict__ startv, int* __restrict__ part, int P, int N) {

    __shared__ int wsum[16];
    const int t = threadIdx.x, lane = t & 63, wv = t >> 6;
    const int d = blockIdx.x * 1024 + t;

    int sc = 0;
    if (d < N) {
        #pragma unroll 4
        for (int p = 0; p < P; ++p) {
            const size_t idx = (size_t)p * NBINS + d;
            const int c = pcnt[idx];
            pcnt[idx] = (unsigned char)sc;
            sc += c;
        }
        cnt[d] = sc;
        int ss = 0;
        #pragma unroll 4
        for (int p = 0; p < P; ++p) ss += psrc[(size_t)p * NBINS + d];
        d2w[d] = rsqrtf(fmaxf((float)ss, 1.0f));
    }

    const int v = sc;          // 0 for d >= N
    int x = v;
    #pragma unroll
    for (int off = 1; off < 64; off <<= 1) { int y = __shfl_up(x, off); if (lane >= off) x += y; }
    if (lane == 63) wsum[wv] = x;
    __syncthreads();
    if (t < 16) {
        int w = wsum[t], xx = w;
        #pragma unroll
        for (int off = 1; off < 16; off <<= 1) { int y = __shfl_up(xx, off); if (t >= off) xx += y; }
        wsum[t] = xx - w;
    }
    __syncthreads();
    int incl = x + wsum[wv];
    if (d < N) startv[d] = incl - v;
    if (t == 1023) part[blockIdx.x] = incl;
}

// shared helper: chunk-offset prefix (nb <= 64) into smem
__device__ __forceinline__ void load_chunkoff(const int* __restrict__ part, int nb,
                                              int* __restrict__ co) {
    if (threadIdx.x < 64) {
        int v = (threadIdx.x < nb) ? part[threadIdx.x] : 0;
        int x = v;
        #pragma unroll
        for (int off = 1; off < 64; off <<= 1) {
            int y = __shfl_up(x, off);
            if ((threadIdx.x & 63) >= off) x += y;
        }
        co[threadIdx.x] = x - v;                 // exclusive
    }
    __syncthreads();
}

// ---------------- K3: edge geometry + DIRECT placement (zero atomics) ------------------------
// rec[pos] = {s|i0<<16, i1|i2<<16, i3|w_bf16<<16, pack}

__global__ __launch_bounds__(256) void edge_kernel(
    const float4* __restrict__ loc4, const float* __restrict__ boundaries,
    const int* __restrict__ lut,
    const int* __restrict__ src, const int* __restrict__ dst,
    const int* __restrict__ inter,
    const unsigned char* __restrict__ rnk8, const unsigned char* __restrict__ pcnt,
    const int* __restrict__ startv, const int* __restrict__ part,
    const float* __restrict__ d2w,
    int4* __restrict__ rec, int E, int nb) {

    __shared__ int lut_s[LUTN];
    __shared__ float bl[64];
    __shared__ int co[64];
    ((int4*)lut_s)[threadIdx.x] = ((const int4*)lut)[threadIdx.x];
    if (threadIdx.x < 64)
        bl[threadIdx.x] = (threadIdx.x < 63) ? boundaries[threadIdx.x] : 3.4e38f;
    load_chunkoff(part, nb, co);   // its __syncthreads also covers lut_s/bl

    const int e = blockIdx.x * 256 + threadIdx.x;
    if (e >= E) return;

    const int s = src[e], d = dst[e];
    const int4 ii = ((const int4*)inter)[e];

    const float4 ps = loc4[s];
    float dist[5];
    {
        float4 pd = loc4[d];
        float dx = pd.x - ps.x, dy = pd.y - ps.y, dz = pd.z - ps.z;
        dist[0] = sqrtf(dx * dx + dy * dy + dz * dz);
    }
    const int id4[4] = {ii.x, ii.y, ii.z, ii.w};
    #pragma unroll
    for (int j = 0; j < 4; ++j) {
        float4 pt = loc4[id4[j]];
        float dx = pt.x - ps.x, dy = pt.y - ps.y, dz = pt.z - ps.z;
        dist[1 + j] = sqrtf(dx * dx + dy * dy + dz * dz);
    }
    unsigned pack = 0;
    #pragma unroll
    for (int q = 0; q < 5; ++q) {
        float dq = dist[q];
        int cell = (int)(dq * LUTSCALE);
        cell = (cell > LUTN - 1) ? (LUTN - 1) : cell;
        int b = lut_s[cell];
        while (b < 63 && bl[b] < dq) ++b;
        while (b > 0 && bl[b - 1] >= dq) --b;
        pack |= ((unsigned)b) << (6 * q);
    }

    const int p = e >> CHSH;                              // chunk id
    const int cbase = pcnt[(size_t)p * NBINS + d];        // chunk-local exclusive base
    const int pos = startv[d] + co[d >> 10] + cbase + (int)rnk8[e];
    const float w = d2w[s];
    unsigned uw = __float_as_uint(w);
    unsigned wb = (uw + 0x7FFFu + ((uw >> 16) & 1u)) & 0xFFFF0000u;   // bf16 in high half
    rec[pos] = make_int4(s | (ii.x << 16), ii.y | (ii.z << 16), ii.w | (int)wb, (int)pack);
}

// ---------------- K4: node gather — 2 records/iter (half-wave split, ushort2/lane) -----------
// lane = h*32 + j : half h handles record 2k+h, lane j handles features {2j, 2j+1}.
// Invalid tail record -> zeroed (w = 0 => exact no-op; ids=0 keep gathers in-bounds).

__global__ __launch_bounds__(256) void node_kernel(
    const unsigned short* __restrict__ featH, const float* __restrict__ M,
    const int* __restrict__ cnt, const int* __restrict__ startv,
    const int* __restrict__ part, const int4* __restrict__ rec,
    float* __restrict__ cat, float* __restrict__ swb, int N, int nb) {

    __shared__ float Ms[4096];
    __shared__ int co[64];
    #pragma unroll
    for (int i = 0; i < 4; ++i)
        ((float4*)Ms)[threadIdx.x + 256 * i] = ((const float4*)M)[threadIdx.x + 256 * i];
    load_chunkoff(part, nb, co);   // includes the __syncthreads for Ms too

    const int lane = threadIdx.x & 63;
    const int h    = lane >> 5;          // half 0/1
    const int j    = lane & 31;          // feature-pair index
    const int wid  = threadIdx.x >> 6;
    const int d    = blockIdx.x * 4 + wid;
    if (d >= N) return;

    const int deg  = __builtin_amdgcn_readfirstlane(cnt[d]);
    const int base = __builtin_amdgcn_readfirstlane(startv[d] + co[d >> 10]);
    const int4* rp = rec + base;

    float a0l = 0.f, a0h = 0.f, a1l = 0.f, a1h = 0.f, sw = 0.f;
    const int kmax = (deg + 1) >> 1;

    #pragma unroll 2
    for (int k = 0; k < kmax; ++k) {
        const int k2 = 2 * k + h;
        int4 r;
        if (k2 < deg) r = rp[k2];
        else          r = make_int4(0, 0, 0, 0);

        const int s  = r.x & 0xFFFF;
        const int i0 = ((unsigned)r.x) >> 16;
        const int i1 = r.y & 0xFFFF;
        const int i2 = ((unsigned)r.y) >> 16;
        const int i3 = r.z & 0xFFFF;
        const float w = __uint_as_float((unsigned)r.z & 0xFFFF0000u);
        const unsigned pk = (unsigned)r.w;

        const unsigned fsu = *(const unsigned*)(featH + (size_t)s  * 64 + 2 * j);
        const unsigned f0u = *(const unsigned*)(featH + (size_t)i0 * 64 + 2 * j);
        const unsigned f1u = *(const unsigned*)(featH + (size_t)i1 * 64 + 2 * j);
        const unsigned f2u = *(const unsigned*)(featH + (size_t)i2 * 64 + 2 * j);
        const unsigned f3u = *(const unsigned*)(featH + (size_t)i3 * 64 + 2 * j);

        const float2 m0 = *(const float2*)&Ms[(pk & 63u) * 64 + 2 * j];
        const float2 m1 = *(const float2*)&Ms[((pk >> 6) & 63u) * 64 + 2 * j];
        const float2 m2 = *(const float2*)&Ms[((pk >> 12) & 63u) * 64 + 2 * j];
        const float2 m3 = *(const float2*)&Ms[((pk >> 18) & 63u) * 64 + 2 * j];
        const float2 m4 = *(const float2*)&Ms[((pk >> 24) & 63u) * 64 + 2 * j];

        const float fsl = __uint_as_float(fsu << 16), fsh = __uint_as_float(fsu & 0xFFFF0000u);
        const float f0l = __uint_as_float(f0u << 16), f0h = __uint_as_float(f0u & 0xFFFF0000u);
        const float f1l = __uint_as_float(f1u << 16), f1h = __uint_as_float(f1u & 0xFFFF0000u);
        const float f2l = __uint_as_float(f2u << 16), f2h = __uint_as_float(f2u & 0xFFFF0000u);
        const float f3l = __uint_as_float(f3u << 16), f3h = __uint_as_float(f3u & 0xFFFF0000u);

        a0l = fmaf(m0.x * fsl, w, a0l);
        a0h = fmaf(m0.y * fsh, w, a0h);
        const float tl = m1.x * f0l + m2.x * f1l + m3.x * f2l + m4.x * f3l;
        const float th = m1.y * f0h + m2.y * f1h + m3.y * f2h + m4.y * f3h;
        a1l = fmaf(0.25f * tl, w, a1l);
        a1h = fmaf(0.25f * th, w, a1h);
        sw += w;
    }

    // cross-half combine: each half adds the other half's partial for the block it stores
    const float b0l = __shfl_xor(a0l, 32, 64);
    const float b0h = __shfl_xor(a0h, 32, 64);
    const float b1l = __shfl_xor(a1l, 32, 64);
    const float b1h = __shfl_xor(a1h, 32, 64);
    const float swt = sw + __shfl_xor(sw, 32, 64);

    if (h == 0) {
        *(float2*)&cat[(size_t)d * 128 + 2 * j]      = make_float2(a0l + b0l, a0h + b0h);
    } else {
        *(float2*)&cat[(size_t)d * 128 + 64 + 2 * j] = make_float2(a1l + b1l, a1h + b1h);
    }
    if (lane == 0) swb[d] = swt;
}

// ---------------- K5: epilogue GEMM  out = d0 * (cat @ agg_w^T + bias*sw) ----------------

__global__ __launch_bounds__(256) void epilogue_kernel(
    const float* __restrict__ cat, const float* __restrict__ agg_w,
    const float* __restrict__ agg_b, const float* __restrict__ swb,
    const int* __restrict__ cnt, float* __restrict__ out, int N) {

    const int lane = threadIdx.x & 63;
    const int wid  = threadIdx.x >> 6;

    float4 aw[32];
    const float4* awp = (const float4*)(agg_w + (size_t)lane * 128);
    #pragma unroll
    for (int i = 0; i < 32; ++i) aw[i] = awp[i];
    const float bias = agg_b[lane];

    const int gw = blockIdx.x * 4 + wid;
    const int stride = gridDim.x * 4;

    for (int d0i = gw; d0i < N; d0i += stride) {
        const int du = __builtin_amdgcn_readfirstlane(d0i);
        const float* cp = cat + (size_t)du * 128;
        float a0 = bias * swb[du], a1 = 0.f, a2 = 0.f, a3 = 0.f;
        #pragma unroll
        for (int k4 = 0; k4 < 32; k4 += 4) {
            float4 c0 = ((const float4*)cp)[k4];
            float4 c1 = ((const float4*)cp)[k4 + 1];
            float4 c2 = ((const float4*)cp)[k4 + 2];
            float4 c3 = ((const float4*)cp)[k4 + 3];
            a0 = fmaf(aw[k4].x, c0.x, a0); a0 = fmaf(aw[k4].y, c0.y, a0);
            a0 = fmaf(aw[k4].z, c0.z, a0); a0 = fmaf(aw[k4].w, c0.w, a0);
            a1 = fmaf(aw[k4+1].x, c1.x, a1); a1 = fmaf(aw[k4+1].y, c1.y, a1);
            a1 = fmaf(aw[k4+1].z, c1.z, a1); a1 = fmaf(aw[k4+1].w, c1.w, a1);
            a2 = fmaf(aw[k4+2].x, c2.x, a2); a2 = fmaf(aw[k4+2].y, c2.y, a2);
            a2 = fmaf(aw[k4+2].z, c2.z, a2); a2 = fmaf(aw[k4+2].w, c2.w, a2);
            a3 = fmaf(aw[k4+3].x, c3.x, a3); a3 = fmaf(aw[k4+3].y, c3.y, a3);
            a3 = fmaf(aw[k4+3].z, c3.z, a3); a3 = fmaf(aw[k4+3].w, c3.w, a3);
        }
        const float d0v = rsqrtf(fmaxf((float)cnt[du], 1.0f));
        out[(size_t)du * 64 + lane] = d0v * ((a0 + a1) + (a2 + a3));
    }
}

// ---------------- launch ----------------

extern "C" void kernel_launch(void* const* d_in, const int* in_sizes, int n_in,
                              void* d_out, int out_size, void* d_ws, size_t ws_size,
                              hipStream_t stream) {
    const float* feat       = (const float*)d_in[0];
    const float* loc        = (const float*)d_in[1];
    const float* boundaries = (const float*)d_in[2];
    const float* embed      = (const float*)d_in[3];
    const float* G_w        = (const float*)d_in[4];
    const float* agg_w      = (const float*)d_in[5];
    const float* agg_b      = (const float*)d_in[6];
    const int*   src        = (const int*)d_in[7];
    const int*   dst        = (const int*)d_in[8];
    const int*   inter      = (const int*)d_in[9];

    const int N = in_sizes[0] / 64;   // 50000 (< 2^16 for id packing; <= NBINS for LDS hist)
    const int E = in_sizes[7];        // 500000

    const int P = (E + (1 << CHSH) - 1) >> CHSH;   // 123 histogram chunks

    char* w = (char*)d_ws;
    auto take = [&](size_t bytes) { char* p = w; w += (bytes + 15) & ~(size_t)15; return p; };
    float*          M      = (float*)take(4096 * 4);
    int*            lut    = (int*)  take(LUTN * 4);
    int*            cnt    = (int*)  take((size_t)N * 4);
    int*            startv = (int*)  take((size_t)N * 4);
    int*            part   = (int*)  take(64 * 4);
    float*          d2w    = (float*)take((size_t)N * 4);
    int4*           rec    = (int4*) take((size_t)E * 16);
    unsigned char*  rnk8   = (unsigned char*)take((size_t)E);
    unsigned char*  pcnt   = (unsigned char*)take((size_t)P * NBINS);
    unsigned char*  psrc   = (unsigned char*)take((size_t)P * NBINS);
    float*          cat    = (float*)take((size_t)N * 128 * 4);
    float*          swb    = (float*)take((size_t)N * 4);
    unsigned short* featH  = (unsigned short*)take((size_t)N * 64 * 2);
    float4*         loc4   = (float4*)take((size_t)N * 16);
    float*          out    = (float*)d_out;

    const int eb = (E + 255) / 256;     // 1954
    const int nb = (N + 1023) / 1024;   // 49 (<= 64 required by chunkoff helper)
    const int PREPB = 512;              // prep-role blocks in front_kernel

    front_kernel<<<P + PREPB, 256, 0, stream>>>(embed, G_w, boundaries, feat, loc,
                                                src, dst, M, lut, featH, loc4,
                                                pcnt, psrc, rnk8, N, E, P, PREPB);
    merge_scan_kernel<<<nb, 1024, 0, stream>>>(pcnt, psrc, cnt, d2w, startv, part, P, N);
    edge_kernel<<<eb, 256, 0, stream>>>(loc4, boundaries, lut, src, dst, inter,
                                        rnk8, pcnt, startv, part, d2w, rec, E, nb);
    node_kernel<<<(N + 3) / 4, 256, 0, stream>>>(featH, M, cnt, startv, part, rec,
                                                 cat, swb, N, nb);
    epilogue_kernel<<<768, 256, 0, stream>>>(cat, agg_w, agg_b, swb, cnt, out, N);
}